// Round 1
// baseline (264.120 us; speedup 1.0000x reference)
//
#include <hip/hip_runtime.h>
#include <hip/hip_bf16.h>

typedef __hip_bfloat16 bf16;
typedef __attribute__((ext_vector_type(4))) float f32x4;
typedef __attribute__((ext_vector_type(8))) __bf16 bf16x8;

#define DEVI static __device__ __forceinline__

// async global->LDS, 16B per lane. LDS dest is wave-uniform base + lane*16.
DEVI void gload_lds16(const void* g, void* l) {
  __builtin_amdgcn_global_load_lds(
      (const __attribute__((address_space(1))) void*)g,
      (__attribute__((address_space(3))) void*)l, 16, 0, 0);
}

// ---------------- f32 -> bf16 converters ----------------
union PK4 { bf16 h[4]; unsigned long long ll; };

DEVI unsigned long long pack4(float4 v) {
  PK4 u;
  u.h[0] = __float2bfloat16(v.x); u.h[1] = __float2bfloat16(v.y);
  u.h[2] = __float2bfloat16(v.z); u.h[3] = __float2bfloat16(v.w);
  return u.ll;
}

__global__ void cvt2_kernel(const float* __restrict__ a, const float* __restrict__ b,
                            bf16* __restrict__ oa, bf16* __restrict__ ob, int n4) {
  int i = blockIdx.x * blockDim.x + threadIdx.x;
  if (i >= n4) return;
  float4 va = reinterpret_cast<const float4*>(a)[i];
  float4 vb = reinterpret_cast<const float4*>(b)[i];
  reinterpret_cast<unsigned long long*>(oa)[i] = pack4(va);
  reinterpret_cast<unsigned long long*>(ob)[i] = pack4(vb);
}

__global__ void cvt4_kernel(const float* __restrict__ a, const float* __restrict__ b,
                            const float* __restrict__ c, const float* __restrict__ d,
                            bf16* __restrict__ oa, bf16* __restrict__ ob,
                            bf16* __restrict__ oc, bf16* __restrict__ od, int n4) {
  int i = blockIdx.x * blockDim.x + threadIdx.x;
  if (i >= n4) return;
  reinterpret_cast<unsigned long long*>(oa)[i] = pack4(reinterpret_cast<const float4*>(a)[i]);
  reinterpret_cast<unsigned long long*>(ob)[i] = pack4(reinterpret_cast<const float4*>(b)[i]);
  reinterpret_cast<unsigned long long*>(oc)[i] = pack4(reinterpret_cast<const float4*>(c)[i]);
  reinterpret_cast<unsigned long long*>(od)[i] = pack4(reinterpret_cast<const float4*>(d)[i]);
}

// ---------------- GEMM: C[M,N] = A[M,K] @ W[N,K]^T + bias ----------------
// MODE 0: C -> bf16 row-major [M,512]
// MODE 1: C -> bf16 transposed vT layout [(b*8+h)*64+d][2048]  (for V)
// MODE 2: C -> f32  out = resid + relu(acc + bias)   (final FFN stage)
// 128x128 tile, BK=64, 4 waves (2x2 of 64x64), 16x16x32 bf16 MFMA.
// LDS tiles [128 rows][64 bf16 = 128B] with XOR swizzle: byte ^= (row&7)<<4,
// applied on the *global source* for global_load_lds and on ds_read (G4/m201 rule 21).
template<int MODE>
__global__ __launch_bounds__(256) void gemm_k(
    const bf16* __restrict__ A, const bf16* __restrict__ W,
    const float* __restrict__ bias,
    bf16* __restrict__ Ob, float* __restrict__ Of, const bf16* __restrict__ resid) {
  constexpr int K = 512;
  __shared__ __align__(16) char smem[32768];
  char* As = smem;
  char* Bs = smem + 16384;
  const int tid = threadIdx.x;
  const int wave = tid >> 6, lane = tid & 63;
  const int bm = blockIdx.x, bn = blockIdx.y;
  const int wm = (wave >> 1) * 64, wn = (wave & 1) * 64;

  const int srow8 = lane >> 3;   // row within 8-row chunk
  const int sslot = lane & 7;    // 16B slot within 128B row

  f32x4 acc[4][4] = {};

  const long Abase = (long)bm * 128 * K;
  const long Wbase = (long)bn * 128 * K;

  for (int kt = 0; kt < K; kt += 64) {
#pragma unroll
    for (int i = 0; i < 4; ++i) {
      int c = wave * 4 + i;            // chunk 0..15 (8 rows x 128B each)
      int row = c * 8 + srow8;
      int gs = sslot ^ (row & 7);      // pre-swizzled source slot
      gload_lds16(A + Abase + (long)row * K + kt + gs * 8, As + c * 1024);
      gload_lds16(W + Wbase + (long)row * K + kt + gs * 8, Bs + c * 1024);
    }
    __syncthreads();
#pragma unroll
    for (int ks = 0; ks < 2; ++ks) {
      bf16x8 af[4], bfv[4];
      int slot = ks * 4 + (lane >> 4);
#pragma unroll
      for (int f = 0; f < 4; ++f) {
        int rowA = wm + f * 16 + (lane & 15);
        af[f] = *reinterpret_cast<const bf16x8*>(As + rowA * 128 + ((slot ^ (rowA & 7)) << 4));
        int rowB = wn + f * 16 + (lane & 15);
        bfv[f] = *reinterpret_cast<const bf16x8*>(Bs + rowB * 128 + ((slot ^ (rowB & 7)) << 4));
      }
#pragma unroll
      for (int mf = 0; mf < 4; ++mf)
#pragma unroll
        for (int nf = 0; nf < 4; ++nf)
          acc[mf][nf] = __builtin_amdgcn_mfma_f32_16x16x32_bf16(af[mf], bfv[nf], acc[mf][nf], 0, 0, 0);
    }
    __syncthreads();
  }

  // epilogue. D layout: col = lane&15, row = (lane>>4)*4 + j  (measured, m89/m91)
#pragma unroll
  for (int nf = 0; nf < 4; ++nf) {
    int col = bn * 128 + wn + nf * 16 + (lane & 15);
    float bia = bias[col];
#pragma unroll
    for (int mf = 0; mf < 4; ++mf) {
#pragma unroll
      for (int j = 0; j < 4; ++j) {
        int row = bm * 128 + wm + mf * 16 + (lane >> 4) * 4 + j;
        float v = acc[mf][nf][j] + bia;
        if (MODE == 0) {
          Ob[(long)row * 512 + col] = __float2bfloat16(v);
        } else if (MODE == 1) {
          int b = row >> 11, s = row & 2047;
          int h = col >> 6, d = col & 63;
          Ob[((long)((b * 8 + h) * 64 + d)) * 2048 + s] = __float2bfloat16(v);
        } else {
          float r = __bfloat162float(resid[(long)row * 512 + col]);
          Of[(long)row * 512 + col] = r + fmaxf(v, 0.f);
        }
      }
    }
  }
}

// ---------------- attention ----------------
// grid: (Sq/64, B*H). 4 waves/block, each wave owns 16 q rows.
// Q proj [B*Sq,512] bf16, K proj [B*Skv,512] bf16, VT [(b*8+h)*64+d][Skv] bf16.
// out1 = q + softmax(q k^T/8) v -> O bf16 [B*Sq,512]
__global__ __launch_bounds__(256) void attn_k(
    const bf16* __restrict__ Q, const bf16* __restrict__ Kp,
    const bf16* __restrict__ VT, bf16* __restrict__ O) {
  __shared__ __align__(16) char smem[8192 + 8192 + 4 * 2048];
  char* Ks = smem;             // [64 kv][64 d] swizzled
  char* Vs = smem + 8192;      // [64 d][64 kv] swizzled
  const int tid = threadIdx.x, wave = tid >> 6, lane = tid & 63;
  char* Ps = smem + 16384 + wave * 2048;  // per-wave P [16 q][64 kv] swizzled
  const int bh = blockIdx.y, b = bh >> 3, h = bh & 7;
  const int qrow0 = blockIdx.x * 64 + wave * 16;
  const long qgbase = ((long)(b * 2048 + qrow0)) * 512 + h * 64;

  // Q A-fragments held in registers for the whole kernel
  bf16x8 aq[2];
#pragma unroll
  for (int ks = 0; ks < 2; ++ks)
    aq[ks] = *reinterpret_cast<const bf16x8*>(Q + qgbase + (long)(lane & 15) * 512 + ks * 32 + (lane >> 4) * 8);

  f32x4 oacc[4] = {};
  float mrow[4] = {-INFINITY, -INFINITY, -INFINITY, -INFINITY};
  float lsum[4] = {0.f, 0.f, 0.f, 0.f};

  const int srow8 = lane >> 3, sslot = lane & 7;

  for (int t = 0; t < 2048; t += 64) {
    // stage K tile (8KB) + V^T tile (8KB): 2+2 chunks per wave
#pragma unroll
    for (int i = 0; i < 2; ++i) {
      int c = wave * 2 + i;
      int row = c * 8 + srow8;
      int gs = sslot ^ (row & 7);
      gload_lds16(Kp + ((long)(b * 2048 + t + row)) * 512 + h * 64 + gs * 8, Ks + c * 1024);
      gload_lds16(VT + ((long)(bh * 64 + row)) * 2048 + t + gs * 8, Vs + c * 1024);
    }
    __syncthreads();

    // S = Q K^T  (16 x 64)
    f32x4 sacc[4] = {};
#pragma unroll
    for (int ks = 0; ks < 2; ++ks) {
      int slot = ks * 4 + (lane >> 4);
#pragma unroll
      for (int nf = 0; nf < 4; ++nf) {
        int row = nf * 16 + (lane & 15);
        bf16x8 bk = *reinterpret_cast<const bf16x8*>(Ks + row * 128 + ((slot ^ (row & 7)) << 4));
        sacc[nf] = __builtin_amdgcn_mfma_f32_16x16x32_bf16(aq[ks], bk, sacc[nf], 0, 0, 0);
      }
    }
#pragma unroll
    for (int nf = 0; nf < 4; ++nf) sacc[nf] *= 0.125f;

    // online softmax (per q-row; cols spread over lane&15 within 16-lane group)
    float mnew[4], alpha[4];
#pragma unroll
    for (int r = 0; r < 4; ++r) {
      float mx = fmaxf(fmaxf(sacc[0][r], sacc[1][r]), fmaxf(sacc[2][r], sacc[3][r]));
      mx = fmaxf(mx, __shfl_xor(mx, 1));
      mx = fmaxf(mx, __shfl_xor(mx, 2));
      mx = fmaxf(mx, __shfl_xor(mx, 4));
      mx = fmaxf(mx, __shfl_xor(mx, 8));
      mnew[r] = fmaxf(mrow[r], mx);
      alpha[r] = __expf(mrow[r] - mnew[r]);
      mrow[r] = mnew[r];
    }
    float p[4][4];
#pragma unroll
    for (int r = 0; r < 4; ++r) {
      float s0 = 0.f;
#pragma unroll
      for (int nf = 0; nf < 4; ++nf) { p[nf][r] = __expf(sacc[nf][r] - mnew[r]); s0 += p[nf][r]; }
      s0 += __shfl_xor(s0, 1);
      s0 += __shfl_xor(s0, 2);
      s0 += __shfl_xor(s0, 4);
      s0 += __shfl_xor(s0, 8);
      lsum[r] = lsum[r] * alpha[r] + s0;
#pragma unroll
      for (int df = 0; df < 4; ++df) oacc[df][r] *= alpha[r];
    }
    // P -> per-wave LDS (swizzled row-major [16][64] bf16), wave-private: no barrier
#pragma unroll
    for (int nf = 0; nf < 4; ++nf) {
#pragma unroll
      for (int r = 0; r < 4; ++r) {
        int prow = (lane >> 4) * 4 + r;
        int pcol = nf * 16 + (lane & 15);
        *reinterpret_cast<bf16*>(Ps + prow * 128 + ((pcol * 2) ^ ((prow & 7) << 4))) = __float2bfloat16(p[nf][r]);
      }
    }
    // O += P V
#pragma unroll
    for (int ks = 0; ks < 2; ++ks) {
      int prow = lane & 15;
      int slot = ks * 4 + (lane >> 4);
      bf16x8 pa = *reinterpret_cast<const bf16x8*>(Ps + prow * 128 + (((slot) ^ (prow & 7)) << 4));
#pragma unroll
      for (int df = 0; df < 4; ++df) {
        int vrow = df * 16 + (lane & 15);
        bf16x8 bv = *reinterpret_cast<const bf16x8*>(Vs + vrow * 128 + ((slot ^ (vrow & 7)) << 4));
        oacc[df] = __builtin_amdgcn_mfma_f32_16x16x32_bf16(pa, bv, oacc[df], 0, 0, 0);
      }
    }
    __syncthreads();
  }

  // epilogue: out1 = q + o/l
#pragma unroll
  for (int df = 0; df < 4; ++df) {
#pragma unroll
    for (int r = 0; r < 4; ++r) {
      int row = (lane >> 4) * 4 + r;
      int col = df * 16 + (lane & 15);
      long g = qgbase + (long)row * 512 + col;
      float qv = __bfloat162float(Q[g]);
      O[g] = __float2bfloat16(qv + oacc[df][r] / lsum[r]);
    }
  }
}

// ---------------- launch ----------------
extern "C" void kernel_launch(void* const* d_in, const int* in_sizes, int n_in,
                              void* d_out, int out_size, void* d_ws, size_t ws_size,
                              hipStream_t stream) {
  const float* query = (const float*)d_in[0];
  const float* keyv  = (const float*)d_in[1];
  const float* Wq = (const float*)d_in[2];
  const float* bq = (const float*)d_in[3];
  const float* Wk = (const float*)d_in[4];
  const float* bk = (const float*)d_in[5];
  const float* Wv = (const float*)d_in[6];
  const float* bv = (const float*)d_in[7];
  const float* Wo = (const float*)d_in[8];
  const float* bo = (const float*)d_in[9];
  float* out = (float*)d_out;
  char* ws = (char*)d_ws;

  bf16* qb  = (bf16*)(ws + 0);         // query bf16      8388608 B
  bf16* kvb = (bf16*)(ws + 8388608);   // key_value bf16  8388608 B
  bf16* wqb = (bf16*)(ws + 16777216);  // 524288 B
  bf16* wkb = (bf16*)(ws + 17301504);
  bf16* wvb = (bf16*)(ws + 17825792);
  bf16* wob = (bf16*)(ws + 18350080);
  bf16* qp  = (bf16*)(ws + 18874368);  // q proj bf16
  bf16* kp  = (bf16*)(ws + 27262976);  // k proj bf16
  bf16* vT  = (bf16*)(ws + 35651584);  // v proj transposed [(b*8+h)*64+d][2048]
  bf16* o1  = (bf16*)(ws + 44040192);  // attn out + q residual, bf16

  cvt2_kernel<<<4096, 256, 0, stream>>>(query, keyv, qb, kvb, 1048576);
  cvt4_kernel<<<256, 256, 0, stream>>>(Wq, Wk, Wv, Wo, wqb, wkb, wvb, wob, 65536);

  dim3 g(64, 4);
  gemm_k<0><<<g, 256, 0, stream>>>(qb,  wqb, bq, qp, nullptr, nullptr);
  gemm_k<0><<<g, 256, 0, stream>>>(kvb, wkb, bk, kp, nullptr, nullptr);
  gemm_k<1><<<g, 256, 0, stream>>>(kvb, wvb, bv, vT, nullptr, nullptr);

  attn_k<<<dim3(32, 32), 256, 0, stream>>>(qp, kp, vT, o1);

  gemm_k<2><<<g, 256, 0, stream>>>(o1, wob, bo, nullptr, out, o1);
}

// Round 2
// 220.620 us; speedup vs baseline: 1.1972x; 1.1972x over previous
//
#include <hip/hip_runtime.h>
#include <hip/hip_bf16.h>

typedef __hip_bfloat16 bf16;
typedef __attribute__((ext_vector_type(4))) float f32x4;
typedef __attribute__((ext_vector_type(16))) float f32x16;
typedef __attribute__((ext_vector_type(8))) __bf16 bf16x8;

#define DEVI static __device__ __forceinline__

DEVI void gload_lds16(const void* g, void* l) {
  __builtin_amdgcn_global_load_lds(
      (const __attribute__((address_space(1))) void*)g,
      (__attribute__((address_space(3))) void*)l, 16, 0, 0);
}

// pack two f32 -> u32 of 2 bf16 (lo = a, hi = b)
DEVI unsigned pkbf(float a, float b) {
  union { __hip_bfloat162 h2; unsigned u; } t;
  t.h2.x = __float2bfloat16(a);
  t.h2.y = __float2bfloat16(b);
  return t.u;
}

// ---------------- f32 -> bf16 converters ----------------
union PK4 { bf16 h[4]; unsigned long long ll; };

DEVI unsigned long long pack4(float4 v) {
  PK4 u;
  u.h[0] = __float2bfloat16(v.x); u.h[1] = __float2bfloat16(v.y);
  u.h[2] = __float2bfloat16(v.z); u.h[3] = __float2bfloat16(v.w);
  return u.ll;
}

__global__ void cvt2_kernel(const float* __restrict__ a, const float* __restrict__ b,
                            bf16* __restrict__ oa, bf16* __restrict__ ob, int n4) {
  int i = blockIdx.x * blockDim.x + threadIdx.x;
  if (i >= n4) return;
  float4 va = reinterpret_cast<const float4*>(a)[i];
  float4 vb = reinterpret_cast<const float4*>(b)[i];
  reinterpret_cast<unsigned long long*>(oa)[i] = pack4(va);
  reinterpret_cast<unsigned long long*>(ob)[i] = pack4(vb);
}

__global__ void cvt4_kernel(const float* __restrict__ a, const float* __restrict__ b,
                            const float* __restrict__ c, const float* __restrict__ d,
                            bf16* __restrict__ oa, bf16* __restrict__ ob,
                            bf16* __restrict__ oc, bf16* __restrict__ od, int n4) {
  int i = blockIdx.x * blockDim.x + threadIdx.x;
  if (i >= n4) return;
  reinterpret_cast<unsigned long long*>(oa)[i] = pack4(reinterpret_cast<const float4*>(a)[i]);
  reinterpret_cast<unsigned long long*>(ob)[i] = pack4(reinterpret_cast<const float4*>(b)[i]);
  reinterpret_cast<unsigned long long*>(oc)[i] = pack4(reinterpret_cast<const float4*>(c)[i]);
  reinterpret_cast<unsigned long long*>(od)[i] = pack4(reinterpret_cast<const float4*>(d)[i]);
}

// ---------------- fused QKV projection GEMM ----------------
// grid (64, 12): zone = by>>2 (0:Q 1:K 2:V), bn = by&3. 128x128 tile, BK=64,
// 4 waves 2x2, 16x16x32 MFMA. LDS rows 128B, slot^(row&7) swizzle (verified 0-conflict R1).
__global__ __launch_bounds__(256) void gemm_qkv(
    const bf16* __restrict__ qb, const bf16* __restrict__ kvb,
    const bf16* __restrict__ wqb, const bf16* __restrict__ wkb, const bf16* __restrict__ wvb,
    const float* __restrict__ bq, const float* __restrict__ bk, const float* __restrict__ bv,
    bf16* __restrict__ qp, bf16* __restrict__ kp, bf16* __restrict__ vT) {
  constexpr int K = 512;
  __shared__ __align__(16) char smem[32768];
  char* As = smem;
  char* Bs = smem + 16384;
  const int tid = threadIdx.x;
  const int wave = tid >> 6, lane = tid & 63;
  const int bm = blockIdx.x;
  const int zone = blockIdx.y >> 2, bn = blockIdx.y & 3;
  const bf16* A = zone ? kvb : qb;
  const bf16* W = (zone == 0) ? wqb : (zone == 1 ? wkb : wvb);
  const float* bias = (zone == 0) ? bq : (zone == 1 ? bk : bv);
  const int wm = (wave >> 1) * 64, wn = (wave & 1) * 64;
  const int srow8 = lane >> 3, sslot = lane & 7;

  f32x4 acc[4][4] = {};
  const long Abase = (long)bm * 128 * K;
  const long Wbase = (long)bn * 128 * K;

  for (int kt = 0; kt < K; kt += 64) {
#pragma unroll
    for (int i = 0; i < 4; ++i) {
      int c = wave * 4 + i;
      int row = c * 8 + srow8;
      int gs = sslot ^ (row & 7);
      gload_lds16(A + Abase + (long)row * K + kt + gs * 8, As + c * 1024);
      gload_lds16(W + Wbase + (long)row * K + kt + gs * 8, Bs + c * 1024);
    }
    __syncthreads();
#pragma unroll
    for (int ks = 0; ks < 2; ++ks) {
      bf16x8 af[4], bfv[4];
      int slot = ks * 4 + (lane >> 4);
#pragma unroll
      for (int f = 0; f < 4; ++f) {
        int rowA = wm + f * 16 + (lane & 15);
        af[f] = *reinterpret_cast<const bf16x8*>(As + rowA * 128 + ((slot ^ (rowA & 7)) << 4));
        int rowB = wn + f * 16 + (lane & 15);
        bfv[f] = *reinterpret_cast<const bf16x8*>(Bs + rowB * 128 + ((slot ^ (rowB & 7)) << 4));
      }
#pragma unroll
      for (int mf = 0; mf < 4; ++mf)
#pragma unroll
        for (int nf = 0; nf < 4; ++nf)
          acc[mf][nf] = __builtin_amdgcn_mfma_f32_16x16x32_bf16(af[mf], bfv[nf], acc[mf][nf], 0, 0, 0);
    }
    __syncthreads();
  }

#pragma unroll
  for (int nf = 0; nf < 4; ++nf) {
    int col = bn * 128 + wn + nf * 16 + (lane & 15);
    float bia = bias[col];
#pragma unroll
    for (int mf = 0; mf < 4; ++mf) {
#pragma unroll
      for (int j = 0; j < 4; ++j) {
        int row = bm * 128 + wm + mf * 16 + (lane >> 4) * 4 + j;
        float v = acc[mf][nf][j] + bia;
        if (zone < 2) {
          bf16* Ob = zone ? kp : qp;
          Ob[(long)row * 512 + col] = __float2bfloat16(v);
        } else {
          int b = row >> 11, s = row & 2047;
          int h = col >> 6, d = col & 63;
          vT[((long)((b * 8 + h) * 64 + d)) * 2048 + s] = __float2bfloat16(v);
        }
      }
    }
  }
}

// ---------------- FFN GEMM: out = resid + relu(resid @ Wo^T + bo) ----------------
// BM=64, BN=128 -> grid (128, 4) = 512 blocks (2/CU). 4 waves 2x2 -> wave 32x64.
__global__ __launch_bounds__(256) void gemm_ffn(
    const bf16* __restrict__ A, const bf16* __restrict__ W,
    const float* __restrict__ bias, float* __restrict__ Of) {
  constexpr int K = 512;
  __shared__ __align__(16) char smem[24576];
  char* As = smem;           // 64 rows x 128B = 8KB
  char* Bs = smem + 8192;    // 128 rows x 128B = 16KB
  const int tid = threadIdx.x;
  const int wave = tid >> 6, lane = tid & 63;
  const int bm = blockIdx.x, bn = blockIdx.y;
  const int wm = (wave >> 1) * 32, wn = (wave & 1) * 64;
  const int srow8 = lane >> 3, sslot = lane & 7;

  f32x4 acc[2][4] = {};
  const long Abase = (long)bm * 64 * K;
  const long Wbase = (long)bn * 128 * K;

  for (int kt = 0; kt < K; kt += 64) {
#pragma unroll
    for (int i = 0; i < 2; ++i) {
      int c = wave * 2 + i;
      int row = c * 8 + srow8;
      int gs = sslot ^ (row & 7);
      gload_lds16(A + Abase + (long)row * K + kt + gs * 8, As + c * 1024);
    }
#pragma unroll
    for (int i = 0; i < 4; ++i) {
      int c = wave * 4 + i;
      int row = c * 8 + srow8;
      int gs = sslot ^ (row & 7);
      gload_lds16(W + Wbase + (long)row * K + kt + gs * 8, Bs + c * 1024);
    }
    __syncthreads();
#pragma unroll
    for (int ks = 0; ks < 2; ++ks) {
      bf16x8 af[2], bfv[4];
      int slot = ks * 4 + (lane >> 4);
#pragma unroll
      for (int f = 0; f < 2; ++f) {
        int rowA = wm + f * 16 + (lane & 15);
        af[f] = *reinterpret_cast<const bf16x8*>(As + rowA * 128 + ((slot ^ (rowA & 7)) << 4));
      }
#pragma unroll
      for (int f = 0; f < 4; ++f) {
        int rowB = wn + f * 16 + (lane & 15);
        bfv[f] = *reinterpret_cast<const bf16x8*>(Bs + rowB * 128 + ((slot ^ (rowB & 7)) << 4));
      }
#pragma unroll
      for (int mf = 0; mf < 2; ++mf)
#pragma unroll
        for (int nf = 0; nf < 4; ++nf)
          acc[mf][nf] = __builtin_amdgcn_mfma_f32_16x16x32_bf16(af[mf], bfv[nf], acc[mf][nf], 0, 0, 0);
    }
    __syncthreads();
  }

#pragma unroll
  for (int nf = 0; nf < 4; ++nf) {
    int col = bn * 128 + wn + nf * 16 + (lane & 15);
    float bia = bias[col];
#pragma unroll
    for (int mf = 0; mf < 2; ++mf) {
#pragma unroll
      for (int j = 0; j < 4; ++j) {
        int row = bm * 64 + wm + mf * 16 + (lane >> 4) * 4 + j;
        float r = __bfloat162float(A[(long)row * 512 + col]);
        Of[(long)row * 512 + col] = r + fmaxf(acc[mf][nf][j] + bia, 0.f);
      }
    }
  }
}

// ---------------- attention (m214-style, swapped QK^T, in-register softmax) ----------------
// grid (16, 32): 4 waves/block, wave owns 32 q rows (q-tile 128). KVBLK=64.
// S^T = mfma32x32x16(K, Q): lane holds S[kv(16 of 32)][q=lane&31].
// softmax in-register; P^T assembled via pk + v_permlane32_swap; O^T = V^T P^T.
__global__ __launch_bounds__(256) void attn_k(
    const bf16* __restrict__ Q, const bf16* __restrict__ Kp,
    const bf16* __restrict__ VT, bf16* __restrict__ O) {
  __shared__ __align__(16) char smem[32768];  // 2 x (Ks 8K + Vs 8K)
  const int tid = threadIdx.x, wave = tid >> 6, lane = tid & 63;
  const int bh = blockIdx.y, b = bh >> 3, h = bh & 7;
  const int q0 = blockIdx.x * 128 + wave * 32;
  const int ql = lane & 31, hl = lane >> 5;
  const long qg = ((long)(b * 2048 + q0 + ql)) * 512 + h * 64;
  const int srow8 = lane >> 3, sslot = lane & 7;

  // Q fragments (B-operand): qf[c] = Q[q][c*16 + hl*8 .. +8]
  bf16x8 qf[4];
#pragma unroll
  for (int c = 0; c < 4; ++c)
    qf[c] = *reinterpret_cast<const bf16x8*>(Q + qg + c * 16 + hl * 8);

  f32x16 oacc[2] = {};
  float m = -INFINITY, l = 0.f;
  const float CEXP = 0.125f * 1.44269504088896f;  // scale * log2(e)

#define STAGE(BUF, T)                                                                   \
  {                                                                                     \
    char* Ksb = smem + (BUF) * 16384;                                                   \
    char* Vsb = Ksb + 8192;                                                             \
    _Pragma("unroll") for (int i = 0; i < 2; ++i) {                                     \
      int c = wave * 2 + i;                                                             \
      int row = c * 8 + srow8;                                                          \
      int gs = sslot ^ (row & 7);                                                       \
      gload_lds16(Kp + ((long)(b * 2048 + (T) * 64 + row)) * 512 + h * 64 + gs * 8,     \
                  Ksb + c * 1024);                                                      \
      gload_lds16(VT + ((long)(bh * 64 + row)) * 2048 + (T) * 64 + gs * 8,              \
                  Vsb + c * 1024);                                                      \
    }                                                                                   \
  }

  STAGE(0, 0)

  for (int t = 0; t < 32; ++t) {
    const int cur = t & 1;
    if (t < 31) {
      STAGE(cur ^ 1, t + 1)
      asm volatile("s_waitcnt vmcnt(4)" ::: "memory");
    } else {
      asm volatile("s_waitcnt vmcnt(0)" ::: "memory");
    }
    asm volatile("s_barrier" ::: "memory");

    char* Ksb = smem + cur * 16384;
    char* Vsb = Ksb + 8192;

    // ---- S^T = K · Q^T  (two 32-kv subtiles) ----
    f32x16 sacc[2] = {};
    __builtin_amdgcn_s_setprio(1);
#pragma unroll
    for (int s = 0; s < 2; ++s) {
#pragma unroll
      for (int c = 0; c < 4; ++c) {
        int row = s * 32 + ql;
        bf16x8 kf = *reinterpret_cast<const bf16x8*>(
            Ksb + row * 128 + (((c * 2 + hl) ^ (row & 7)) << 4));
        sacc[s] = __builtin_amdgcn_mfma_f32_32x32x16_bf16(kf, qf[c], sacc[s], 0, 0, 0);
      }
    }
    __builtin_amdgcn_s_setprio(0);

    // ---- online softmax, in-register ----
    float pmax = -3.0e38f;
#pragma unroll
    for (int s = 0; s < 2; ++s)
#pragma unroll
      for (int i = 0; i < 16; ++i) pmax = fmaxf(pmax, sacc[s][i]);
    pmax = fmaxf(pmax, __shfl_xor(pmax, 32));

    // defer-max (T13): skip O/l rescale while pmax <= m + 8/CEXP  (P bounded by 2^8)
    if (!__all(pmax - m <= 44.3614195558365f)) {
      float mn = fmaxf(m, pmax);
      float al = exp2f((m - mn) * CEXP);
      m = mn;
      l *= al;
#pragma unroll
      for (int d = 0; d < 2; ++d)
#pragma unroll
        for (int i = 0; i < 16; ++i) oacc[d][i] *= al;
    }
    float nmC = -m * CEXP;
    float p[32];
    float ps = 0.f;
#pragma unroll
    for (int s = 0; s < 2; ++s)
#pragma unroll
      for (int i = 0; i < 16; ++i) {
        float pv = exp2f(fmaf(sacc[s][i], CEXP, nmC));
        p[s * 16 + i] = pv;
        ps += pv;
      }
    ps += __shfl_xor(ps, 32);
    l += ps;

    // ---- P^T fragments via pack + permlane32_swap; O^T += V^T · P^T ----
    __builtin_amdgcn_s_setprio(1);
#pragma unroll
    for (int s = 0; s < 2; ++s) {
#pragma unroll
      for (int jj = 0; jj < 2; ++jj) {
        int base = s * 16 + jj * 8;
        unsigned w0 = pkbf(p[base + 0], p[base + 1]);
        unsigned w1 = pkbf(p[base + 2], p[base + 3]);
        unsigned w2 = pkbf(p[base + 4], p[base + 5]);
        unsigned w3 = pkbf(p[base + 6], p[base + 7]);
        // swap hi-half(w0) <-> lo-half(w2): w0 -> [w0_lo, w2_lo], w2 -> [w0_hi, w2_hi]
        asm("v_permlane32_swap_b32 %0, %1" : "+v"(w0), "+v"(w2));
        asm("v_permlane32_swap_b32 %0, %1" : "+v"(w1), "+v"(w3));
        union { unsigned u[4]; bf16x8 v; } pf;
        pf.u[0] = w0; pf.u[1] = w1; pf.u[2] = w2; pf.u[3] = w3;
        int j = s * 2 + jj;  // 16-kv chunk
#pragma unroll
        for (int dblk = 0; dblk < 2; ++dblk) {
          int row = dblk * 32 + ql;
          bf16x8 vf = *reinterpret_cast<const bf16x8*>(
              Vsb + row * 128 + (((j * 2 + hl) ^ (row & 7)) << 4));
          oacc[dblk] = __builtin_amdgcn_mfma_f32_32x32x16_bf16(vf, pf.v, oacc[dblk], 0, 0, 0);
        }
      }
    }
    __builtin_amdgcn_s_setprio(0);

    asm volatile("s_barrier" ::: "memory");
  }

  // ---- epilogue: out = q + O/l ; lane holds O^T[d][q=lane&31] ----
  float rl = 1.0f / l;
#pragma unroll
  for (int dblk = 0; dblk < 2; ++dblk) {
#pragma unroll
    for (int g = 0; g < 4; ++g) {
      int d0 = dblk * 32 + g * 8 + hl * 4;
      const long ga = qg + d0;
      union { ushort4 s; unsigned short u[4]; } qin, ov;
      qin.s = *reinterpret_cast<const ushort4*>(Q + ga);
#pragma unroll
      for (int i = 0; i < 4; ++i) {
        float qvf = __uint_as_float((unsigned)qin.u[i] << 16);
        float r = qvf + oacc[dblk][g * 4 + i] * rl;
        bf16 hb = __float2bfloat16(r);
        ov.u[i] = *reinterpret_cast<unsigned short*>(&hb);
      }
      *reinterpret_cast<ushort4*>(O + ga) = ov.s;
    }
  }
}

// ---------------- launch ----------------
extern "C" void kernel_launch(void* const* d_in, const int* in_sizes, int n_in,
                              void* d_out, int out_size, void* d_ws, size_t ws_size,
                              hipStream_t stream) {
  const float* query = (const float*)d_in[0];
  const float* keyv  = (const float*)d_in[1];
  const float* Wq = (const float*)d_in[2];
  const float* bq = (const float*)d_in[3];
  const float* Wk = (const float*)d_in[4];
  const float* bk = (const float*)d_in[5];
  const float* Wv = (const float*)d_in[6];
  const float* bv = (const float*)d_in[7];
  const float* Wo = (const float*)d_in[8];
  const float* bo = (const float*)d_in[9];
  float* out = (float*)d_out;
  char* ws = (char*)d_ws;

  bf16* qb  = (bf16*)(ws + 0);
  bf16* kvb = (bf16*)(ws + 8388608);
  bf16* wqb = (bf16*)(ws + 16777216);
  bf16* wkb = (bf16*)(ws + 17301504);
  bf16* wvb = (bf16*)(ws + 17825792);
  bf16* wob = (bf16*)(ws + 18350080);
  bf16* qp  = (bf16*)(ws + 18874368);
  bf16* kp  = (bf16*)(ws + 27262976);
  bf16* vT  = (bf16*)(ws + 35651584);
  bf16* o1  = (bf16*)(ws + 44040192);

  cvt2_kernel<<<4096, 256, 0, stream>>>(query, keyv, qb, kvb, 1048576);
  cvt4_kernel<<<256, 256, 0, stream>>>(Wq, Wk, Wv, Wo, wqb, wkb, wvb, wob, 65536);

  gemm_qkv<<<dim3(64, 12), 256, 0, stream>>>(qb, kvb, wqb, wkb, wvb, bq, bk, bv, qp, kp, vT);

  attn_k<<<dim3(16, 32), 256, 0, stream>>>(qp, kp, vT, o1);

  gemm_ffn<<<dim3(128, 4), 256, 0, stream>>>(o1, wob, bo, out);
}

// Round 4
// 192.983 us; speedup vs baseline: 1.3686x; 1.1432x over previous
//
#include <hip/hip_runtime.h>
#include <hip/hip_bf16.h>

typedef __hip_bfloat16 bf16;
typedef __attribute__((ext_vector_type(4))) float f32x4;
typedef __attribute__((ext_vector_type(16))) float f32x16;
typedef __attribute__((ext_vector_type(8))) __bf16 bf16x8;

#define DEVI static __device__ __forceinline__

DEVI void gload_lds16(const void* g, void* l) {
  __builtin_amdgcn_global_load_lds(
      (const __attribute__((address_space(1))) void*)g,
      (__attribute__((address_space(3))) void*)l, 16, 0, 0);
}

DEVI unsigned pkbf(float a, float b) {
  union { __hip_bfloat162 h2; unsigned u; } t;
  t.h2.x = __float2bfloat16(a);
  t.h2.y = __float2bfloat16(b);
  return t.u;
}

// ---------------- merged f32 -> bf16 converter ----------------
union PK4 { bf16 h[4]; unsigned long long ll; };

DEVI unsigned long long pack4(float4 v) {
  PK4 u;
  u.h[0] = __float2bfloat16(v.x); u.h[1] = __float2bfloat16(v.y);
  u.h[2] = __float2bfloat16(v.z); u.h[3] = __float2bfloat16(v.w);
  return u.ll;
}

__global__ void cvt_all(const float* __restrict__ q, const float* __restrict__ kv,
                        const float* __restrict__ wq, const float* __restrict__ wk,
                        const float* __restrict__ wv, const float* __restrict__ wo,
                        bf16* __restrict__ oq, bf16* __restrict__ okv,
                        bf16* __restrict__ owq, bf16* __restrict__ owk,
                        bf16* __restrict__ owv, bf16* __restrict__ owo) {
  int bid = blockIdx.x;
  if (bid < 4096) {
    int i = bid * 256 + threadIdx.x;  // < 1048576
    reinterpret_cast<unsigned long long*>(oq)[i]  = pack4(reinterpret_cast<const float4*>(q)[i]);
    reinterpret_cast<unsigned long long*>(okv)[i] = pack4(reinterpret_cast<const float4*>(kv)[i]);
  } else {
    int i = (bid - 4096) * 256 + threadIdx.x;  // < 65536
    reinterpret_cast<unsigned long long*>(owq)[i] = pack4(reinterpret_cast<const float4*>(wq)[i]);
    reinterpret_cast<unsigned long long*>(owk)[i] = pack4(reinterpret_cast<const float4*>(wk)[i]);
    reinterpret_cast<unsigned long long*>(owv)[i] = pack4(reinterpret_cast<const float4*>(wv)[i]);
    reinterpret_cast<unsigned long long*>(owo)[i] = pack4(reinterpret_cast<const float4*>(wo)[i]);
  }
}

// ---------------- fused QKV projection GEMM, 2-phase double-buffered ----------------
// grid (64, 12): zone = by>>2 (0:Q 1:K 2:V), bn = by&3. 128x128 tile, BK=64,
// 4 waves 2x2, 16x16x32 MFMA. LDS 2 x (As 16K + Bs 16K) = 64KB.
__global__ __launch_bounds__(256) void gemm_qkv(
    const bf16* __restrict__ qb, const bf16* __restrict__ kvb,
    const bf16* __restrict__ wqb, const bf16* __restrict__ wkb, const bf16* __restrict__ wvb,
    const float* __restrict__ bq, const float* __restrict__ bk, const float* __restrict__ bv,
    bf16* __restrict__ qp, bf16* __restrict__ kp, bf16* __restrict__ vT) {
  constexpr int K = 512;
  __shared__ __align__(16) char smem[65536];
  const int tid = threadIdx.x;
  const int wave = tid >> 6, lane = tid & 63;
  const int bm = blockIdx.x;
  const int zone = blockIdx.y >> 2, bn = blockIdx.y & 3;
  const bf16* A = zone ? kvb : qb;
  const bf16* W = (zone == 0) ? wqb : (zone == 1 ? wkb : wvb);
  const float* bias = (zone == 0) ? bq : (zone == 1 ? bk : bv);
  const int wm = (wave >> 1) * 64, wn = (wave & 1) * 64;
  const int srow8 = lane >> 3, sslot = lane & 7;

  f32x4 acc[4][4] = {};

  // hoisted per-lane global stage pointers (advance +64 per K-step)
  const bf16* ap[4];
  const bf16* wp[4];
  char* adst[4];
  char* bdst[4];
#pragma unroll
  for (int i = 0; i < 4; ++i) {
    int c = wave * 4 + i;
    int row = c * 8 + srow8;
    int gs = sslot ^ (row & 7);
    ap[i] = A + (long)(bm * 128 + row) * K + gs * 8;
    wp[i] = W + (long)(bn * 128 + row) * K + gs * 8;
    adst[i] = smem + c * 1024;
    bdst[i] = smem + 16384 + c * 1024;
  }

  // hoisted ds_read offsets (within one 16KB tile)
  int aoff[2][4], boff[2][4];
#pragma unroll
  for (int ks = 0; ks < 2; ++ks)
#pragma unroll
    for (int f = 0; f < 4; ++f) {
      int r = f * 16 + (lane & 15);
      int sw = ((ks * 4 + (lane >> 4)) ^ (r & 7)) << 4;
      aoff[ks][f] = (wm + r) * 128 + sw;
      boff[ks][f] = (wn + r) * 128 + sw;
    }

#define GSTAGE(BUF)                                                       \
  _Pragma("unroll") for (int i = 0; i < 4; ++i) {                         \
    gload_lds16(ap[i], adst[i] + (BUF) * 32768);                          \
    gload_lds16(wp[i], bdst[i] + (BUF) * 32768);                          \
    ap[i] += 64; wp[i] += 64;                                             \
  }

#define GBODY(BUF, LAST)                                                  \
  {                                                                       \
    if (!(LAST)) {                                                        \
      GSTAGE((BUF) ^ 1)                                                   \
      asm volatile("s_waitcnt vmcnt(8)" ::: "memory");                    \
    } else {                                                              \
      asm volatile("s_waitcnt vmcnt(0)" ::: "memory");                    \
    }                                                                     \
    asm volatile("s_barrier" ::: "memory");                               \
    const char* Asb = smem + (BUF) * 32768;                               \
    const char* Bsb = Asb + 16384;                                        \
    _Pragma("unroll") for (int ks = 0; ks < 2; ++ks) {                    \
      bf16x8 af[4], bfv[4];                                               \
      _Pragma("unroll") for (int f = 0; f < 4; ++f) {                     \
        af[f]  = *reinterpret_cast<const bf16x8*>(Asb + aoff[ks][f]);     \
        bfv[f] = *reinterpret_cast<const bf16x8*>(Bsb + boff[ks][f]);     \
      }                                                                   \
      _Pragma("unroll") for (int mf = 0; mf < 4; ++mf)                    \
        _Pragma("unroll") for (int nf = 0; nf < 4; ++nf)                  \
          acc[mf][nf] = __builtin_amdgcn_mfma_f32_16x16x32_bf16(          \
              af[mf], bfv[nf], acc[mf][nf], 0, 0, 0);                     \
    }                                                                     \
    asm volatile("s_barrier" ::: "memory");                               \
  }

  GSTAGE(0)
#pragma unroll 1
  for (int kt = 0; kt < 8; kt += 2) {
    GBODY(0, false)
    GBODY(1, kt + 1 == 7)
  }
#undef GSTAGE
#undef GBODY

#pragma unroll
  for (int nf = 0; nf < 4; ++nf) {
    int col = bn * 128 + wn + nf * 16 + (lane & 15);
    float bia = bias[col];
#pragma unroll
    for (int mf = 0; mf < 4; ++mf) {
      int row0 = bm * 128 + wm + mf * 16 + (lane >> 4) * 4;
      if (zone < 2) {
        bf16* Ob = zone ? kp : qp;
#pragma unroll
        for (int j = 0; j < 4; ++j)
          Ob[(long)(row0 + j) * 512 + col] = __float2bfloat16(acc[mf][nf][j] + bia);
      } else {
        // vT[(b*8+h)*64+d][s], pack 4 consecutive s into one 8B store
        int b = row0 >> 11, s0 = row0 & 2047;
        int h = col >> 6, d = col & 63;
        union { ushort4 s; unsigned short u[4]; } pk;
#pragma unroll
        for (int j = 0; j < 4; ++j) {
          bf16 hv = __float2bfloat16(acc[mf][nf][j] + bia);
          pk.u[j] = *reinterpret_cast<unsigned short*>(&hv);
        }
        *reinterpret_cast<ushort4*>(vT + ((long)((b * 8 + h) * 64 + d)) * 2048 + s0) = pk.s;
      }
    }
  }
}

// ---------------- FFN GEMM: out = resid + relu(resid @ Wo^T + bo), 2-phase ----------------
// BM=64, BN=128 -> grid (128, 4). 4 waves 2x2 -> wave 32x64. LDS 2x24KB = 48KB.
__global__ __launch_bounds__(256) void gemm_ffn(
    const bf16* __restrict__ A, const bf16* __restrict__ W,
    const float* __restrict__ bias, float* __restrict__ Of) {
  constexpr int K = 512;
  __shared__ __align__(16) char smem[49152];
  const int tid = threadIdx.x;
  const int wave = tid >> 6, lane = tid & 63;
  const int bm = blockIdx.x, bn = blockIdx.y;
  const int wm = (wave >> 1) * 32, wn = (wave & 1) * 64;
  const int srow8 = lane >> 3, sslot = lane & 7;

  f32x4 acc[2][4] = {};

  const bf16* ap[2];
  const bf16* wp[4];
  char* adst[2];
  char* bdst[4];
#pragma unroll
  for (int i = 0; i < 2; ++i) {
    int c = wave * 2 + i;
    int row = c * 8 + srow8;
    int gs = sslot ^ (row & 7);
    ap[i] = A + (long)(bm * 64 + row) * K + gs * 8;
    adst[i] = smem + c * 1024;
  }
#pragma unroll
  for (int i = 0; i < 4; ++i) {
    int c = wave * 4 + i;
    int row = c * 8 + srow8;
    int gs = sslot ^ (row & 7);
    wp[i] = W + (long)(bn * 128 + row) * K + gs * 8;
    bdst[i] = smem + 8192 + c * 1024;
  }

  int aoff[2][2], boff[2][4];
#pragma unroll
  for (int ks = 0; ks < 2; ++ks) {
#pragma unroll
    for (int f = 0; f < 2; ++f) {
      int r = f * 16 + (lane & 15);
      aoff[ks][f] = (wm + r) * 128 + (((ks * 4 + (lane >> 4)) ^ (r & 7)) << 4);
    }
#pragma unroll
    for (int f = 0; f < 4; ++f) {
      int r = f * 16 + (lane & 15);
      boff[ks][f] = (wn + r) * 128 + (((ks * 4 + (lane >> 4)) ^ (r & 7)) << 4);
    }
  }

#define FSTAGE(BUF)                                                       \
  {                                                                       \
    _Pragma("unroll") for (int i = 0; i < 2; ++i) {                       \
      gload_lds16(ap[i], adst[i] + (BUF) * 24576);                        \
      ap[i] += 64;                                                        \
    }                                                                     \
    _Pragma("unroll") for (int i = 0; i < 4; ++i) {                       \
      gload_lds16(wp[i], bdst[i] + (BUF) * 24576);                        \
      wp[i] += 64;                                                        \
    }                                                                     \
  }

#define FBODY(BUF, LAST)                                                  \
  {                                                                       \
    if (!(LAST)) {                                                        \
      FSTAGE((BUF) ^ 1)                                                   \
      asm volatile("s_waitcnt vmcnt(6)" ::: "memory");                    \
    } else {                                                              \
      asm volatile("s_waitcnt vmcnt(0)" ::: "memory");                    \
    }                                                                     \
    asm volatile("s_barrier" ::: "memory");                               \
    const char* Asb = smem + (BUF) * 24576;                               \
    const char* Bsb = Asb + 8192;                                         \
    _Pragma("unroll") for (int ks = 0; ks < 2; ++ks) {                    \
      bf16x8 af[2], bfv[4];                                               \
      _Pragma("unroll") for (int f = 0; f < 2; ++f)                       \
        af[f] = *reinterpret_cast<const bf16x8*>(Asb + aoff[ks][f]);      \
      _Pragma("unroll") for (int f = 0; f < 4; ++f)                       \
        bfv[f] = *reinterpret_cast<const bf16x8*>(Bsb + boff[ks][f]);     \
      _Pragma("unroll") for (int mf = 0; mf < 2; ++mf)                    \
        _Pragma("unroll") for (int nf = 0; nf < 4; ++nf)                  \
          acc[mf][nf] = __builtin_amdgcn_mfma_f32_16x16x32_bf16(          \
              af[mf], bfv[nf], acc[mf][nf], 0, 0, 0);                     \
    }                                                                     \
    asm volatile("s_barrier" ::: "memory");                               \
  }

  FSTAGE(0)
#pragma unroll 1
  for (int kt = 0; kt < 8; kt += 2) {
    FBODY(0, false)
    FBODY(1, kt + 1 == 7)
  }
#undef FSTAGE
#undef FBODY

#pragma unroll
  for (int nf = 0; nf < 4; ++nf) {
    int col = bn * 128 + wn + nf * 16 + (lane & 15);
    float bia = bias[col];
#pragma unroll
    for (int mf = 0; mf < 2; ++mf) {
#pragma unroll
      for (int j = 0; j < 4; ++j) {
        int row = bm * 64 + wm + mf * 16 + (lane >> 4) * 4 + j;
        float r = __bfloat162float(A[(long)row * 512 + col]);
        Of[(long)row * 512 + col] = r + fmaxf(acc[mf][nf][j] + bia, 0.f);
      }
    }
  }
}

// ---------------- attention (swapped QK^T, in-register softmax, MFMA row-sum) ----------------
// grid (16, 32): 4 waves/block, wave owns 32 q rows. KVBLK=64, double-buffered K/V LDS.
__global__ __launch_bounds__(256) void attn_k(
    const bf16* __restrict__ Q, const bf16* __restrict__ Kp,
    const bf16* __restrict__ VT, bf16* __restrict__ O) {
  __shared__ __align__(16) char smem[32768];  // buf: Ks 8K + Vs 8K, x2
  const int tid = threadIdx.x, wave = tid >> 6, lane = tid & 63;
  const int bh = blockIdx.y, b = bh >> 3, h = bh & 7;
  const int q0 = blockIdx.x * 128 + wave * 32;
  const int ql = lane & 31, hl = lane >> 5;
  const long qg = ((long)(b * 2048 + q0 + ql)) * 512 + h * 64;
  const int srow8 = lane >> 3, sslot = lane & 7;

  bf16x8 qf[4];
#pragma unroll
  for (int c = 0; c < 4; ++c)
    qf[c] = *reinterpret_cast<const bf16x8*>(Q + qg + c * 16 + hl * 8);

  bf16x8 ones;
#pragma unroll
  for (int j = 0; j < 8; ++j) ones[j] = (__bf16)1.0f;

  f32x16 oacc[2] = {};
  f32x16 lacc = {};
  float m = -INFINITY;
  const float CEXP = 0.125f * 1.44269504088896f;

  // hoisted stage pointers and LDS dests
  const bf16* kgp[2];
  const bf16* vgp[2];
  char* kdst[2];
  char* vdst[2];
#pragma unroll
  for (int i = 0; i < 2; ++i) {
    int c = wave * 2 + i;
    int row = c * 8 + srow8;
    int gs = sslot ^ (row & 7);
    kgp[i] = Kp + ((long)(b * 2048 + row)) * 512 + h * 64 + gs * 8;
    vgp[i] = VT + ((long)(bh * 64 + row)) * 2048 + gs * 8;
    kdst[i] = smem + c * 1024;
    vdst[i] = smem + 8192 + c * 1024;
  }

  // hoisted ds_read offsets: same geometry for K and V tiles
  int ofs[2][4];
#pragma unroll
  for (int s = 0; s < 2; ++s)
#pragma unroll
    for (int c = 0; c < 4; ++c) {
      int row = s * 32 + ql;
      ofs[s][c] = row * 128 + (((c * 2 + hl) ^ (row & 7)) << 4);
    }

#define ASTAGE(BUF)                                                       \
  _Pragma("unroll") for (int i = 0; i < 2; ++i) {                         \
    gload_lds16(kgp[i], kdst[i] + (BUF) * 16384);                         \
    gload_lds16(vgp[i], vdst[i] + (BUF) * 16384);                         \
    kgp[i] += 32768; vgp[i] += 64;                                        \
  }

#define ABODY(BUF, LAST)                                                  \
  {                                                                       \
    if (!(LAST)) {                                                        \
      ASTAGE((BUF) ^ 1)                                                   \
      asm volatile("s_waitcnt vmcnt(4)" ::: "memory");                    \
    } else {                                                              \
      asm volatile("s_waitcnt vmcnt(0)" ::: "memory");                    \
    }                                                                     \
    asm volatile("s_barrier" ::: "memory");                               \
    const char* Kb = smem + (BUF) * 16384;                                \
    const char* Vb = Kb + 8192;                                           \
    f32x16 sacc[2] = {};                                                  \
    __builtin_amdgcn_s_setprio(1);                                        \
    _Pragma("unroll") for (int s = 0; s < 2; ++s)                         \
      _Pragma("unroll") for (int c = 0; c < 4; ++c) {                     \
        bf16x8 kf = *reinterpret_cast<const bf16x8*>(Kb + ofs[s][c]);     \
        sacc[s] = __builtin_amdgcn_mfma_f32_32x32x16_bf16(                \
            kf, qf[c], sacc[s], 0, 0, 0);                                 \
      }                                                                   \
    __builtin_amdgcn_s_setprio(0);                                        \
    float pmax = fmaxf(sacc[0][0], sacc[0][1]);                           \
    _Pragma("unroll") for (int i = 2; i < 16; i += 2)                     \
      pmax = fmaxf(fmaxf(pmax, sacc[0][i]), sacc[0][i + 1]);              \
    _Pragma("unroll") for (int i = 0; i < 16; i += 2)                     \
      pmax = fmaxf(fmaxf(pmax, sacc[1][i]), sacc[1][i + 1]);              \
    pmax = fmaxf(pmax, __shfl_xor(pmax, 32));                             \
    if (!__all(pmax - m <= 44.3614195558365f)) {                          \
      float mn = fmaxf(m, pmax);                                          \
      float al = exp2f((m - mn) * CEXP);                                  \
      m = mn;                                                             \
      _Pragma("unroll") for (int i = 0; i < 16; ++i) {                    \
        oacc[0][i] *= al; oacc[1][i] *= al; lacc[i] *= al;                \
      }                                                                   \
    }                                                                     \
    float nmC = -m * CEXP;                                                \
    float p[32];                                                          \
    _Pragma("unroll") for (int s = 0; s < 2; ++s)                         \
      _Pragma("unroll") for (int i = 0; i < 16; ++i)                      \
        p[s * 16 + i] = exp2f(fmaf(sacc[s][i], CEXP, nmC));               \
    __builtin_amdgcn_s_setprio(1);                                        \
    _Pragma("unroll") for (int s = 0; s < 2; ++s)                         \
      _Pragma("unroll") for (int jj = 0; jj < 2; ++jj) {                  \
        int base = s * 16 + jj * 8;                                       \
        unsigned w0 = pkbf(p[base + 0], p[base + 1]);                     \
        unsigned w1 = pkbf(p[base + 2], p[base + 3]);                     \
        unsigned w2 = pkbf(p[base + 4], p[base + 5]);                     \
        unsigned w3 = pkbf(p[base + 6], p[base + 7]);                     \
        asm("v_permlane32_swap_b32 %0, %1" : "+v"(w0), "+v"(w2));         \
        asm("v_permlane32_swap_b32 %0, %1" : "+v"(w1), "+v"(w3));         \
        union { unsigned u[4]; bf16x8 v; } pf;                            \
        pf.u[0] = w0; pf.u[1] = w1; pf.u[2] = w2; pf.u[3] = w3;           \
        lacc = __builtin_amdgcn_mfma_f32_32x32x16_bf16(                   \
            ones, pf.v, lacc, 0, 0, 0);                                   \
        int j = s * 2 + jj;                                               \
        _Pragma("unroll") for (int dblk = 0; dblk < 2; ++dblk) {          \
          bf16x8 vf = *reinterpret_cast<const bf16x8*>(Vb + ofs[dblk][j]);\
          oacc[dblk] = __builtin_amdgcn_mfma_f32_32x32x16_bf16(           \
              vf, pf.v, oacc[dblk], 0, 0, 0);                             \
        }                                                                 \
      }                                                                   \
    __builtin_amdgcn_s_setprio(0);                                        \
    asm volatile("s_barrier" ::: "memory");                               \
  }

  ASTAGE(0)
#pragma unroll 1
  for (int tt = 0; tt < 16; ++tt) {
    ABODY(0, false)
    ABODY(1, tt == 15)
  }
#undef ASTAGE
#undef ABODY

  float rl = 1.0f / lacc[0];
#pragma unroll
  for (int dblk = 0; dblk < 2; ++dblk) {
#pragma unroll
    for (int g = 0; g < 4; ++g) {
      int d0 = dblk * 32 + g * 8 + hl * 4;
      const long ga = qg + d0;
      union { ushort4 s; unsigned short u[4]; } qin, ov;
      qin.s = *reinterpret_cast<const ushort4*>(Q + ga);
#pragma unroll
      for (int i = 0; i < 4; ++i) {
        float qvf = __uint_as_float((unsigned)qin.u[i] << 16);
        float r = qvf + oacc[dblk][g * 4 + i] * rl;
        bf16 hb = __float2bfloat16(r);
        ov.u[i] = *reinterpret_cast<unsigned short*>(&hb);
      }
      *reinterpret_cast<ushort4*>(O + ga) = ov.s;
    }
  }
}

// ---------------- launch ----------------
extern "C" void kernel_launch(void* const* d_in, const int* in_sizes, int n_in,
                              void* d_out, int out_size, void* d_ws, size_t ws_size,
                              hipStream_t stream) {
  const float* query = (const float*)d_in[0];
  const float* keyv  = (const float*)d_in[1];
  const float* Wq = (const float*)d_in[2];
  const float* bq = (const float*)d_in[3];
  const float* Wk = (const float*)d_in[4];
  const float* bk = (const float*)d_in[5];
  const float* Wv = (const float*)d_in[6];
  const float* bv = (const float*)d_in[7];
  const float* Wo = (const float*)d_in[8];
  const float* bo = (const float*)d_in[9];
  float* out = (float*)d_out;
  char* ws = (char*)d_ws;

  bf16* qb  = (bf16*)(ws + 0);
  bf16* kvb = (bf16*)(ws + 8388608);
  bf16* wqb = (bf16*)(ws + 16777216);
  bf16* wkb = (bf16*)(ws + 17301504);
  bf16* wvb = (bf16*)(ws + 17825792);
  bf16* wob = (bf16*)(ws + 18350080);
  bf16* qp  = (bf16*)(ws + 18874368);
  bf16* kp  = (bf16*)(ws + 27262976);
  bf16* vT  = (bf16*)(ws + 35651584);
  bf16* o1  = (bf16*)(ws + 44040192);

  cvt_all<<<4352, 256, 0, stream>>>(query, keyv, Wq, Wk, Wv, Wo,
                                    qb, kvb, wqb, wkb, wvb, wob);

  gemm_qkv<<<dim3(64, 12), 256, 0, stream>>>(qb, kvb, wqb, wkb, wvb, bq, bk, bv, qp, kp, vT);

  attn_k<<<dim3(16, 32), 256, 0, stream>>>(qp, kp, vT, o1);

  gemm_ffn<<<dim3(128, 4), 256, 0, stream>>>(o1, wob, bo, out);
}